// Round 15
// baseline (576.273 us; speedup 1.0000x reference)
//
#include <hip/hip_runtime.h>
#include <cmath>
#include <cstdint>
#include <cstddef>

namespace {
constexpr int kB = 4;
constexpr int kS = 2048;
constexpr int kD = 768;
constexpr int kH = 12;
constexpr int kHD = 64;
constexpr int k3D = 3 * kD;   // 2304
constexpr float kNeg = -1000000000.0f;
constexpr float kDelta = 0.25f;   // rescue margin >= 2 * bf16 dot error bound
}

// Faithful fp32 masking affine: s = a + NEG*(1-a), no fma contraction so the
// rounding sequence matches numpy's elementwise ops. (Identical to rounds 1-14.)
__device__ __forceinline__ float mask_affine(float a) {
#pragma clang fp contract(off)
    const float u = 1.0f - a;
    return a + kNeg * u;
}

__device__ __forceinline__ short bf16rne_s(float f) {
    uint32_t u = __builtin_bit_cast(uint32_t, f);
    u += 0x7FFFu + ((u >> 16) & 1u);
    return (short)(u >> 16);
}
__device__ __forceinline__ float bf16tof(short h) {
    const uint32_t u = ((uint32_t)(unsigned short)h) << 16;
    return __builtin_bit_cast(float, u);
}

// ---------------------------------------------------------------------------
// EXACT fp32 tiled GEMM with bias (Q,K columns — selection-critical).
// r10/r14 geometry (256 threads, 8x8 microtile, BK=16, dbuf, 1 barrier/tile).
// Round-15 changes (value-exact):
//  * As staging via in-wave 4x4 shuffle transpose: 8x ds_write_b32 ->
//    2x ds_write_b128 (LDS-pipe-bound kernel; writes were ~8% of LDS issue).
//    As CONTENT is bit-identical -> frozen k-ascending fmaf chain unchanged.
//  * SWZ: XCD-aware 1D grid decode (id&7 = XCD, 8 row-panels per XCD) for
//    x row-panel L2 reuse (FETCH was 113 MB vs ~30 ideal).
// ---------------------------------------------------------------------------
template <int BM, int BN, int BK, int TM, int TN, bool SWZ>
__global__ __launch_bounds__(BM * BN / (TM * TN))
void gemm_bias_kernel(const float* __restrict__ A, const float* __restrict__ Bm,
                      const float* __restrict__ bias, float* __restrict__ C,
                      int M, int K, int ldb, int ldc)
{
    constexpr int THREADS = BM * BN / (TM * TN);
    constexpr int TX = BN / TN;
    constexpr int TY = THREADS / TX;
    static_assert(TX == 16 && TY * TM == BM, "geometry");
    static_assert(BK == 16 && THREADS == 256, "transpose-staging mapping");
    constexpr int AF4 = BM * BK / (THREADS * 4);
    constexpr int BF4 = BK * BN / (THREADS * 4);
    constexpr int BSTR = BK * TN + 4;

    __shared__ float As[2][BK][BM + 4];
    __shared__ float Bs[2][TX][BSTR];

    const int tid = threadIdx.x;
    const int tx = tid % TX, ty = tid / TX;

    int bxs, bys;
    if (SWZ) {
        // 1D grid; nby = M/BM row-panels, split 8 ways across XCDs.
        const int nby = M / BM;
        const int per = nby >> 3;           // panels per XCD (nby % 8 == 0)
        const int id = blockIdx.x;
        const int xcd = id & 7, i2 = id >> 3;
        bxs = i2 / per;
        bys = xcd * per + (i2 % per);
    } else {
        bxs = blockIdx.x;
        bys = blockIdx.y;
    }
    const int m0 = bys * BM, n0 = bxs * BN;

    float4 pa[AF4], pb[BF4];
    auto load_tiles = [&](int k0) {
#pragma unroll
        for (int it = 0; it < AF4; ++it) {
            const int e = (tid + it * THREADS) * 4;
            const int row = e / BK, col = e % BK;
            pa[it] = *reinterpret_cast<const float4*>(
                &A[(size_t)(m0 + row) * K + (k0 + col)]);
        }
#pragma unroll
        for (int it = 0; it < BF4; ++it) {
            const int e = (tid + it * THREADS) * 4;
            const int row = e / BN, col = e % BN;
            pb[it] = *reinterpret_cast<const float4*>(
                &Bm[(size_t)(k0 + row) * ldb + (n0 + col)]);
        }
    };
    // As commit: lanes {l, l+4, l+8, l+12} hold rows r0..r0+3 at the same
    // k-chunk c=(tid&3)*4. Two shfl_xor butterfly phases transpose the 4x4
    // block so lane j holds column c+j across the 4 rows -> one b128 write.
    auto commit = [&](int buf) {
#pragma unroll
        for (int it = 0; it < AF4; ++it) {
            const int e = (tid + it * THREADS) * 4;
            const int row = e / BK;          // tid/4 (+64 for it=1)
            const int col = e % BK;          // (tid&3)*4
            const int j = (tid >> 2) & 3;    // lane-in-group
            float v0 = pa[it].x, v1 = pa[it].y, v2 = pa[it].z, v3 = pa[it].w;
            {   // phase 1: lane-bit0 (xor 4) <-> element-bit0
                const bool odd = (j & 1) != 0;
                float s0 = odd ? v0 : v1;
                float s1 = odd ? v2 : v3;
                s0 = __shfl_xor(s0, 4);
                s1 = __shfl_xor(s1, 4);
                if (odd) { v0 = s0; v2 = s1; } else { v1 = s0; v3 = s1; }
            }
            {   // phase 2: lane-bit1 (xor 8) <-> element-bit1
                const bool hi2 = (j & 2) != 0;
                float s0 = hi2 ? v0 : v2;
                float s1 = hi2 ? v1 : v3;
                s0 = __shfl_xor(s0, 8);
                s1 = __shfl_xor(s1, 8);
                if (hi2) { v0 = s0; v1 = s1; } else { v2 = s0; v3 = s1; }
            }
            const int r0 = row & ~3;
            const float4 w = {v0, v1, v2, v3};
            *reinterpret_cast<float4*>(&As[buf][col + j][r0]) = w;
        }
#pragma unroll
        for (int it = 0; it < BF4; ++it) {
            const int e = (tid + it * THREADS) * 4;
            const int row = e / BN, col = e % BN;
            const int g = col / TN, off = col % TN;
            *reinterpret_cast<float4*>(&Bs[buf][g][row * TN + off]) = pb[it];
        }
    };

    float acc[TM][TN];
#pragma unroll
    for (int i = 0; i < TM; ++i)
#pragma unroll
        for (int j = 0; j < TN; ++j) acc[i][j] = 0.0f;

    load_tiles(0);
    commit(0);
    load_tiles(BK);
    __syncthreads();

    int cur = 0;
    for (int k0 = 0; k0 < K; k0 += BK) {
        const bool has_next = (k0 + BK < K);
        if (has_next) {
            commit(cur ^ 1);
            if (k0 + 2 * BK < K) load_tiles(k0 + 2 * BK);
        }
#pragma unroll
        for (int kk = 0; kk < BK; ++kk) {
            float a[TM], b[TN];
#pragma unroll
            for (int i = 0; i < TM; i += 4) {
                const float4 v = *reinterpret_cast<const float4*>(
                    &As[cur][kk][ty * TM + i]);
                a[i] = v.x; a[i + 1] = v.y; a[i + 2] = v.z; a[i + 3] = v.w;
            }
#pragma unroll
            for (int j = 0; j < TN; j += 4) {
                const float4 v = *reinterpret_cast<const float4*>(
                    &Bs[cur][tx][kk * TN + j]);
                b[j] = v.x; b[j + 1] = v.y; b[j + 2] = v.z; b[j + 3] = v.w;
            }
#pragma unroll
            for (int i = 0; i < TM; ++i)
#pragma unroll
                for (int j = 0; j < TN; ++j)
                    acc[i][j] = fmaf(a[i], b[j], acc[i][j]);
        }
        if (has_next) __syncthreads();
        cur ^= 1;
    }

#pragma unroll
    for (int i = 0; i < TM; ++i) {
        const int m = m0 + ty * TM + i;
#pragma unroll
        for (int j = 0; j < TN; ++j) {
            const int n = n0 + tx * TN + j;
            C[(size_t)m * ldc + n] = acc[i][j] + bias[n];
        }
    }
}

// ---------------------------------------------------------------------------
// bf16-split MFMA GEMM with bias (V projection + output projection — NOT
// selection-critical). Unchanged from round 10.
// ---------------------------------------------------------------------------
__global__ __launch_bounds__(256)
void gemm_mfma_kernel(const float* __restrict__ A, const float* __restrict__ Bm,
                      const float* __restrict__ bias, float* __restrict__ C,
                      int M, int K, int ldb, int ldc)
{
    using f32x4 = __attribute__((ext_vector_type(4))) float;
    using s16x8 = __attribute__((ext_vector_type(8))) short;
    constexpr int BM = 128, BN = 64, BK = 32;
    constexpr int AST = 40;

    __shared__ unsigned short Ah[2][BM][AST];
    __shared__ unsigned short Al[2][BM][AST];
    __shared__ unsigned short Bh[2][BN][AST];

    const int tid = threadIdx.x;
    const int wave = tid >> 6, lane = tid & 63;
    const int jq = lane & 15, hi = lane >> 4;
    const int m0 = blockIdx.y * BM, n0 = blockIdx.x * BN;

    float4 pa[4], pb[2];
    auto load_tiles = [&](int k0) {
#pragma unroll
        for (int it = 0; it < 4; ++it) {
            const int e = (tid + it * 256) * 4;
            const int row = e / BK, col = e % BK;
            pa[it] = *reinterpret_cast<const float4*>(
                &A[(size_t)(m0 + row) * K + (k0 + col)]);
        }
#pragma unroll
        for (int it = 0; it < 2; ++it) {
            const int e = (tid + it * 256) * 4;
            const int krow = e / BN, ncol = e % BN;
            pb[it] = *reinterpret_cast<const float4*>(
                &Bm[(size_t)(k0 + krow) * ldb + (n0 + ncol)]);
        }
    };
    auto commit = [&](int buf) {
#pragma unroll
        for (int it = 0; it < 4; ++it) {
            const int e = (tid + it * 256) * 4;
            const int row = e / BK, col = e % BK;
            const float v[4] = {pa[it].x, pa[it].y, pa[it].z, pa[it].w};
            ushort4 uh, ul;
            unsigned short* ph = &uh.x;
            unsigned short* pl = &ul.x;
#pragma unroll
            for (int r = 0; r < 4; ++r) {
                const short hb = bf16rne_s(v[r]);
                ph[r] = (unsigned short)hb;
                pl[r] = (unsigned short)bf16rne_s(v[r] - bf16tof(hb));
            }
            *reinterpret_cast<ushort4*>(&Ah[buf][row][col]) = uh;
            *reinterpret_cast<ushort4*>(&Al[buf][row][col]) = ul;
        }
#pragma unroll
        for (int it = 0; it < 2; ++it) {
            const int e = (tid + it * 256) * 4;
            const int krow = e / BN, ncol = e % BN;
            Bh[buf][ncol + 0][krow] = (unsigned short)bf16rne_s(pb[it].x);
            Bh[buf][ncol + 1][krow] = (unsigned short)bf16rne_s(pb[it].y);
            Bh[buf][ncol + 2][krow] = (unsigned short)bf16rne_s(pb[it].z);
            Bh[buf][ncol + 3][krow] = (unsigned short)bf16rne_s(pb[it].w);
        }
    };

    f32x4 acc[2][4];
#pragma unroll
    for (int i = 0; i < 2; ++i)
#pragma unroll
        for (int j = 0; j < 4; ++j) acc[i][j] = {0.f, 0.f, 0.f, 0.f};

    load_tiles(0);
    commit(0);
    load_tiles(BK);
    __syncthreads();

    int cur = 0;
    for (int k0 = 0; k0 < K; k0 += BK) {
        const bool has_next = (k0 + BK < K);
        if (has_next) {
            commit(cur ^ 1);
            if (k0 + 2 * BK < K) load_tiles(k0 + 2 * BK);
        }
        s16x8 ahf[2], alf[2], bhf[4];
#pragma unroll
        for (int i = 0; i < 2; ++i) {
            ahf[i] = *reinterpret_cast<const s16x8*>(
                &Ah[cur][wave * 32 + i * 16 + jq][hi * 8]);
            alf[i] = *reinterpret_cast<const s16x8*>(
                &Al[cur][wave * 32 + i * 16 + jq][hi * 8]);
        }
#pragma unroll
        for (int j = 0; j < 4; ++j)
            bhf[j] = *reinterpret_cast<const s16x8*>(
                &Bh[cur][j * 16 + jq][hi * 8]);
#pragma unroll
        for (int i = 0; i < 2; ++i)
#pragma unroll
            for (int j = 0; j < 4; ++j) {
                f32x4 c = acc[i][j];
                c = __builtin_amdgcn_mfma_f32_16x16x32_bf16(ahf[i], bhf[j], c, 0, 0, 0);
                c = __builtin_amdgcn_mfma_f32_16x16x32_bf16(alf[i], bhf[j], c, 0, 0, 0);
                acc[i][j] = c;
            }
        if (has_next) __syncthreads();
        cur ^= 1;
    }

#pragma unroll
    for (int i = 0; i < 2; ++i) {
        const int mbase = m0 + wave * 32 + i * 16 + hi * 4;
#pragma unroll
        for (int j = 0; j < 4; ++j) {
            const int n = n0 + j * 16 + jq;
            const float bv = bias[n];
#pragma unroll
            for (int r = 0; r < 4; ++r)
                C[(size_t)(mbase + r) * ldc + n] = acc[i][j][r] + bv;
        }
    }
}

// ---------------------------------------------------------------------------
// Per-key V suffix sums: vsuf[b][h][k][d] = sum_{j>=k} V[b][j][h*64+d].
// ---------------------------------------------------------------------------
__global__ __launch_bounds__(256)
void vsuf_kernel(const float* __restrict__ qkv, float* __restrict__ vsuf)
{
    const int h = blockIdx.x, b = blockIdx.y;
    const int lane = threadIdx.x & 63, wave = threadIdx.x >> 6;
    const float* vp = qkv + (size_t)b * kS * k3D + 2 * kD + h * kHD;
    float* op = vsuf + (size_t)(b * kH + h) * kS * kHD;
    __shared__ float csum[4][64];

    const int kBeg = wave * 512, kEnd = kBeg + 512;
    float s = 0.0f;
#pragma unroll 8
    for (int k = kBeg; k < kEnd; ++k)
        s += vp[(size_t)k * k3D + lane];
    csum[wave][lane] = s;
    __syncthreads();

    float run = 0.0f;
    for (int w = wave + 1; w < 4; ++w) run += csum[w][lane];
#pragma unroll 8
    for (int k = kEnd - 1; k >= kBeg; --k) {
        run += vp[(size_t)k * k3D + lane];
        op[(size_t)k * kHD + lane] = run;
    }
}

// ---------------------------------------------------------------------------
// Attention: TWO-PASS bf16-MFMA approximate scan + exact-fp32 rescue.
// Unchanged from round 14 (measured-good; selection bit-exact vs rounds 1-13).
// ---------------------------------------------------------------------------
__global__ __launch_bounds__(256, 3)
void attn_mfma_kernel(const float* __restrict__ qkv,
                      const float* __restrict__ vsuf,
                      float* __restrict__ ctx)
{
    using f32x4 = __attribute__((ext_vector_type(4))) float;
    using s16x8 = __attribute__((ext_vector_type(8))) short;

    const int id = blockIdx.x;
    const int bh = id % (kB * kH);
    const int t  = id / (kB * kH);
    const int b = bh / kH, h = bh % kH;

    const int tid = threadIdx.x;
    const int wave = tid >> 6, lane = tid & 63;
    const int jq = lane & 15, hi = lane >> 4;
    const int qrow = wave * 16 + jq;
    const int qglob = t * 64 + qrow;

    __shared__ float Qf[64][68];
    __shared__ float Kf[64][68];
    __shared__ unsigned short Kb[64][72];
    __shared__ float Msh[64];
    __shared__ float MgS[64];
    __shared__ int   CgS[64], I0S[64], I1S[64];

    const float* qp = qkv + (size_t)b * kS * k3D + h * kHD;
    const float* kp = qp + kD;
    const float* vp = qp + 2 * kD;

    // stage Q tile, prescaled by 0.125 (exact power of two, same as r1)
#pragma unroll
    for (int i = 0; i < 4; ++i) {
        const int f4 = tid + i * 256;
        const int r = f4 >> 4, d4 = f4 & 15;
        float4 v = *reinterpret_cast<const float4*>(
            &qp[(size_t)(t * 64 + r) * k3D + d4 * 4]);
        v.x *= 0.125f; v.y *= 0.125f; v.z *= 0.125f; v.w *= 0.125f;
        *reinterpret_cast<float4*>(&Qf[r][d4 * 4]) = v;
    }
    __syncthreads();

    auto mkfrag = [&](const float* p) {
        const float4 a = *reinterpret_cast<const float4*>(p);
        const float4 c = *reinterpret_cast<const float4*>(p + 4);
        s16x8 r;
        r[0] = bf16rne_s(a.x); r[1] = bf16rne_s(a.y);
        r[2] = bf16rne_s(a.z); r[3] = bf16rne_s(a.w);
        r[4] = bf16rne_s(c.x); r[5] = bf16rne_s(c.y);
        r[6] = bf16rne_s(c.z); r[7] = bf16rne_s(c.w);
        return r;
    };

    const s16x8 bq0 = mkfrag(&Qf[qrow][hi * 8]);
    const s16x8 bq1 = mkfrag(&Qf[qrow][32 + hi * 8]);

    // stage one K tile as bf16 only (pass 1)
    auto stage_kb = [&](int kt) {
#pragma unroll
        for (int i = 0; i < 4; ++i) {
            const int f4 = tid + i * 256;
            const int r = f4 >> 4, d4 = f4 & 15;
            const float4 v = *reinterpret_cast<const float4*>(
                &kp[(size_t)(kt * 64 + r) * k3D + d4 * 4]);
            ushort4 u;
            u.x = (unsigned short)bf16rne_s(v.x);
            u.y = (unsigned short)bf16rne_s(v.y);
            u.z = (unsigned short)bf16rne_s(v.z);
            u.w = (unsigned short)bf16rne_s(v.w);
            *reinterpret_cast<ushort4*>(&Kb[r][d4 * 4]) = u;
        }
    };
    // stage K tile as bf16 AND fp32 (pass 2: fp32 needed for exact rescue)
    auto stage_both = [&](int kt) {
#pragma unroll
        for (int i = 0; i < 4; ++i) {
            const int f4 = tid + i * 256;
            const int r = f4 >> 4, d4 = f4 & 15;
            const float4 v = *reinterpret_cast<const float4*>(
                &kp[(size_t)(kt * 64 + r) * k3D + d4 * 4]);
            *reinterpret_cast<float4*>(&Kf[r][d4 * 4]) = v;
            ushort4 u;
            u.x = (unsigned short)bf16rne_s(v.x);
            u.y = (unsigned short)bf16rne_s(v.y);
            u.z = (unsigned short)bf16rne_s(v.z);
            u.w = (unsigned short)bf16rne_s(v.w);
            *reinterpret_cast<ushort4*>(&Kb[r][d4 * 4]) = u;
        }
    };

    auto score_tile = [&](f32x4* acc) {
#pragma unroll
        for (int g = 0; g < 4; ++g) {
            const s16x8 a0 = *reinterpret_cast<const s16x8*>(
                &Kb[g * 16 + jq][hi * 8]);
            const s16x8 a1 = *reinterpret_cast<const s16x8*>(
                &Kb[g * 16 + jq][32 + hi * 8]);
            f32x4 c = {0.f, 0.f, 0.f, 0.f};
            c = __builtin_amdgcn_mfma_f32_16x16x32_bf16(a0, bq0, c, 0, 0, 0);
            c = __builtin_amdgcn_mfma_f32_16x16x32_bf16(a1, bq1, c, 0, 0, 0);
            acc[g] = c;
        }
    };

    // ---- pass 1: approximate per-query causal max (bf16 tiles only) ----
    float mt = -INFINITY;
    for (int kt = 0; kt <= t; ++kt) {
        __syncthreads();
        stage_kb(kt);
        __syncthreads();
        f32x4 acc[4];
        score_tile(acc);
#pragma unroll
        for (int g = 0; g < 4; ++g)
#pragma unroll
            for (int r = 0; r < 4; ++r) {
                const int key = kt * 64 + g * 16 + hi * 4 + r;
                if (key <= qglob) mt = fmaxf(mt, acc[g][r]);
            }
    }
    mt = fmaxf(mt, __shfl_xor(mt, 16));
    mt = fmaxf(mt, __shfl_xor(mt, 32));
    if (hi == 0) Msh[wave * 16 + jq] = mt;
    __syncthreads();
    const float thr = Msh[wave * 16 + jq] - kDelta;

    // ---- pass 2: exact rescue of candidates (fp32 chain from LDS Kf) ----
    float m = -INFINITY;
    int cnt = 0, i0 = -1, i1 = -1;
    for (int kt = 0; kt <= t; ++kt) {
        __syncthreads();
        stage_both(kt);
        __syncthreads();
        f32x4 acc[4];
        score_tile(acc);
#pragma unroll
        for (int g = 0; g < 4; ++g)
#pragma unroll
            for (int r = 0; r < 4; ++r) {
                const int key = kt * 64 + g * 16 + hi * 4 + r;
                if (key <= qglob && acc[g][r] > thr) {
                    const float* qr = &Qf[qrow][0];
                    const float* kr = &Kf[key - kt * 64][0];
                    float dot = 0.0f;
#pragma unroll
                    for (int d4 = 0; d4 < 16; ++d4) {
                        const float4 q4 = *reinterpret_cast<const float4*>(qr + d4 * 4);
                        const float4 k4 = *reinterpret_cast<const float4*>(kr + d4 * 4);
                        dot = fmaf(q4.x, k4.x, dot);
                        dot = fmaf(q4.y, k4.y, dot);
                        dot = fmaf(q4.z, k4.z, dot);
                        dot = fmaf(q4.w, k4.w, dot);
                    }
                    const float s = mask_affine(dot);
                    const bool upd = (s > m), tie = (s == m);
                    i1 = upd ? -1 : ((tie && cnt == 1) ? key : i1);
                    i0 = upd ? key : i0;
                    cnt = upd ? 1 : (tie ? cnt + 1 : cnt);
                    m = upd ? s : m;
                }
            }
    }

    // merge the 4 lanes sharing each query column
#pragma unroll
    for (int off = 16; off <= 32; off <<= 1) {
        const float mo = __shfl_xor(m, off);
        const int co = __shfl_xor(cnt, off);
        const int o0 = __shfl_xor(i0, off);
        const int o1 = __shfl_xor(i1, off);
        if (mo > m) { m = mo; cnt = co; i0 = o0; i1 = o1; }
        else if (mo == m && co > 0) {
            if (cnt == 0) { i0 = o0; i1 = o1; }
            else if (cnt == 1) { i1 = o0; }
            cnt += co;
        }
    }
    if (hi == 0) {
        MgS[wave * 16 + jq] = m; CgS[wave * 16 + jq] = cnt;
        I0S[wave * 16 + jq] = i0; I1S[wave * 16 + jq] = i1;
    }
    __syncthreads();

    // ---- epilogue: 4 threads per query, 16 dims each ----
    const int qloc = tid >> 2, qtr = tid & 3;
    const int qi = t * 64 + qloc;
    float mg = MgS[qloc];
    int fcnt = CgS[qloc], f0 = I0S[qloc], f1 = I1S[qloc];

    bool addsuf = false;
    if (qi < kS - 1) {
        const bool lt = (mg < kNeg), eq = (mg == kNeg);
        if (lt)      { fcnt = kS - 1 - qi; f0 = -1; f1 = -1; addsuf = true; }
        else if (eq) { fcnt += kS - 1 - qi; addsuf = true; }
    }

    float4 a4[4];
#pragma unroll
    for (int i = 0; i < 4; ++i) a4[i] = {0.f, 0.f, 0.f, 0.f};

    if (f0 >= 0) {
        const float* vr = vp + (size_t)f0 * k3D + qtr * 16;
#pragma unroll
        for (int i = 0; i < 4; ++i) {
            const float4 v = *reinterpret_cast<const float4*>(vr + i * 4);
            a4[i].x += v.x; a4[i].y += v.y; a4[i].z += v.z; a4[i].w += v.w;
        }
    }
    if (f1 >= 0) {
        const float* vr = vp + (size_t)f1 * k3D + qtr * 16;
#pragma unroll
        for (int i = 0; i < 4; ++i) {
            const float4 v = *reinterpret_cast<const float4*>(vr + i * 4);
            a4[i].x += v.x; a4[i].y += v.y; a4[i].z += v.z; a4[i].w += v.w;
        }
    }
    if (addsuf) {
        const float* sp = vsuf + ((size_t)(b * kH + h) * kS + (qi + 1)) * kHD
                          + qtr * 16;
#pragma unroll
        for (int i = 0; i < 4; ++i) {
            const float4 v = *reinterpret_cast<const float4*>(sp + i * 4);
            a4[i].x += v.x; a4[i].y += v.y; a4[i].z += v.z; a4[i].w += v.w;
        }
    }

    float* op = ctx + ((size_t)b * kS + qi) * kD + h * kHD + qtr * 16;
    const float fc = (float)fcnt;
#pragma unroll
    for (int i = 0; i < 4; ++i) {
        const float4 r = {a4[i].x / fc, a4[i].y / fc, a4[i].z / fc, a4[i].w / fc};
        *reinterpret_cast<float4*>(op + i * 4) = r;
    }
}

// ---------------------------------------------------------------------------
extern "C" void kernel_launch(void* const* d_in, const int* in_sizes, int n_in,
                              void* d_out, int out_size, void* d_ws, size_t ws_size,
                              hipStream_t stream)
{
    const float* x     = (const float*)d_in[0];
    const float* W_qkv = (const float*)d_in[1];
    const float* b_qkv = (const float*)d_in[2];
    const float* W_o   = (const float*)d_in[3];
    const float* b_o   = (const float*)d_in[4];
    float* out = (float*)d_out;

    // workspace: qkv [8192][2304] (75.5 MB) + ctx [8192][768] (25 MB).
    // vsuf (25.2 MB) lives in d_out, fully overwritten by the final GEMM.
    float* qkv  = (float*)d_ws;
    float* ctx  = qkv + (size_t)kB * kS * k3D;
    float* vsuf = out;

    // 1a) Q,K columns: EXACT fp32 GEMM (selection-critical, chain frozen)
    //     1D grid, XCD-swizzled: 12 x-blocks x 64 y-panels = 768 blocks.
    {
        gemm_bias_kernel<128, 128, 16, 8, 8, true><<<dim3(768), 256, 0, stream>>>(
            x, W_qkv, b_qkv, qkv, kB * kS, kD, k3D, k3D);
    }
    // 1b) V columns: staged-split bf16 MFMA GEMM (not selection-critical)
    {
        dim3 grid(kD / 64, (kB * kS) / 128);
        gemm_mfma_kernel<<<grid, 256, 0, stream>>>(
            x, W_qkv + 2 * kD, b_qkv + 2 * kD, qkv + 2 * kD,
            kB * kS, kD, k3D, k3D);
    }
    // 1c) per-key V suffix sums (for the all-masked-dominated rows)
    {
        dim3 grid(kH, kB);
        vsuf_kernel<<<grid, 256, 0, stream>>>(qkv, vsuf);
    }
    // 2) attention: two-pass MFMA approx scan (bf16-at-staging) + exact fp32
    //    rescue from LDS (selection identical to rounds 1-14)
    {
        attn_mfma_kernel<<<dim3((kS / 64) * kB * kH), 256, 0, stream>>>(
            qkv, vsuf, ctx);
    }
    // 3) out = ctx @ W_o + b_o : staged-split bf16 MFMA GEMM
    {
        dim3 grid(kD / 64, (kB * kS) / 128);
        gemm_mfma_kernel<<<grid, 256, 0, stream>>>(
            ctx, W_o, b_o, out, kB * kS, kD, kD, kD);
    }
}

// Round 16
// 475.807 us; speedup vs baseline: 1.2111x; 1.2111x over previous
//
#include <hip/hip_runtime.h>
#include <cmath>
#include <cstdint>
#include <cstddef>

namespace {
constexpr int kB = 4;
constexpr int kS = 2048;
constexpr int kD = 768;
constexpr int kH = 12;
constexpr int kHD = 64;
constexpr int k3D = 3 * kD;   // 2304
constexpr float kNeg = -1000000000.0f;
constexpr float kDelta = 0.25f;   // rescue margin >= 2 * bf16 dot error bound
constexpr int kNQK = 1536;        // Q,K columns

// workspace layout (bytes)
constexpr size_t kOfsQkv = 0;
constexpr size_t kOfsCtx = (size_t)kB * kS * k3D * 4;                 // 75.5MB
constexpr size_t kOfsXh  = kOfsCtx + (size_t)kB * kS * kD * 4;        // +25.2MB
constexpr size_t kSzX    = (size_t)kB * kS * kD * 2;                  // 12.6MB
constexpr size_t kOfsWh  = kOfsXh + 3 * kSzX;
constexpr size_t kSzW    = (size_t)kD * kNQK * 2;                     // 2.36MB
constexpr size_t kNeedWs = kOfsWh + 3 * kSzW;                         // 145.5MB
}

// Faithful fp32 masking affine (identical to rounds 1-15).
__device__ __forceinline__ float mask_affine(float a) {
#pragma clang fp contract(off)
    const float u = 1.0f - a;
    return a + kNeg * u;
}

__device__ __forceinline__ short bf16rne_s(float f) {
    uint32_t u = __builtin_bit_cast(uint32_t, f);
    u += 0x7FFFu + ((u >> 16) & 1u);
    return (short)(u >> 16);
}
__device__ __forceinline__ float bf16tof(short h) {
    const uint32_t u = ((uint32_t)(unsigned short)h) << 16;
    return __builtin_bit_cast(float, u);
}
// exact 3-way bf16 split: v == h + m + l up to 2^-24 relative
__device__ __forceinline__ void split3(float v, unsigned short& h,
                                       unsigned short& m, unsigned short& l) {
    const short hs = bf16rne_s(v);
    const float r1 = v - bf16tof(hs);
    const short ms = bf16rne_s(r1);
    const float r2 = r1 - bf16tof(ms);
    h = (unsigned short)hs;
    m = (unsigned short)ms;
    l = (unsigned short)bf16rne_s(r2);
}

// ---------------------------------------------------------------------------
// EXACT fp32 tiled GEMM with bias — FALLBACK path only (used when ws_size is
// too small for the split arrays). Byte-identical arithmetic to rounds 1-15.
// ---------------------------------------------------------------------------
template <int BM, int BN, int BK, int TM, int TN>
__global__ __launch_bounds__(BM * BN / (TM * TN))
void gemm_bias_kernel(const float* __restrict__ A, const float* __restrict__ Bm,
                      const float* __restrict__ bias, float* __restrict__ C,
                      int M, int K, int ldb, int ldc)
{
    constexpr int THREADS = BM * BN / (TM * TN);
    constexpr int TX = BN / TN;
    constexpr int TY = THREADS / TX;
    static_assert(TX == 16 && TY * TM == BM, "geometry");
    constexpr int AF4 = BM * BK / (THREADS * 4);
    constexpr int BF4 = BK * BN / (THREADS * 4);
    constexpr int BSTR = BK * TN + 4;

    __shared__ float As[2][BK][BM + 4];
    __shared__ float Bs[2][TX][BSTR];

    const int tid = threadIdx.x;
    const int tx = tid % TX, ty = tid / TX;
    const int m0 = blockIdx.y * BM, n0 = blockIdx.x * BN;

    float4 pa[AF4], pb[BF4];
    auto load_tiles = [&](int k0) {
#pragma unroll
        for (int it = 0; it < AF4; ++it) {
            const int e = (tid + it * THREADS) * 4;
            const int row = e / BK, col = e % BK;
            pa[it] = *reinterpret_cast<const float4*>(
                &A[(size_t)(m0 + row) * K + (k0 + col)]);
        }
#pragma unroll
        for (int it = 0; it < BF4; ++it) {
            const int e = (tid + it * THREADS) * 4;
            const int row = e / BN, col = e % BN;
            pb[it] = *reinterpret_cast<const float4*>(
                &Bm[(size_t)(k0 + row) * ldb + (n0 + col)]);
        }
    };
    auto commit = [&](int buf) {
#pragma unroll
        for (int it = 0; it < AF4; ++it) {
            const int e = (tid + it * THREADS) * 4;
            const int row = e / BK, col = e % BK;
            As[buf][col + 0][row] = pa[it].x;
            As[buf][col + 1][row] = pa[it].y;
            As[buf][col + 2][row] = pa[it].z;
            As[buf][col + 3][row] = pa[it].w;
        }
#pragma unroll
        for (int it = 0; it < BF4; ++it) {
            const int e = (tid + it * THREADS) * 4;
            const int row = e / BN, col = e % BN;
            const int g = col / TN, off = col % TN;
            *reinterpret_cast<float4*>(&Bs[buf][g][row * TN + off]) = pb[it];
        }
    };

    float acc[TM][TN];
#pragma unroll
    for (int i = 0; i < TM; ++i)
#pragma unroll
        for (int j = 0; j < TN; ++j) acc[i][j] = 0.0f;

    load_tiles(0);
    commit(0);
    load_tiles(BK);
    __syncthreads();

    int cur = 0;
    for (int k0 = 0; k0 < K; k0 += BK) {
        const bool has_next = (k0 + BK < K);
        if (has_next) {
            commit(cur ^ 1);
            if (k0 + 2 * BK < K) load_tiles(k0 + 2 * BK);
        }
#pragma unroll
        for (int kk = 0; kk < BK; ++kk) {
            float a[TM], b[TN];
#pragma unroll
            for (int i = 0; i < TM; i += 4) {
                const float4 v = *reinterpret_cast<const float4*>(
                    &As[cur][kk][ty * TM + i]);
                a[i] = v.x; a[i + 1] = v.y; a[i + 2] = v.z; a[i + 3] = v.w;
            }
#pragma unroll
            for (int j = 0; j < TN; j += 4) {
                const float4 v = *reinterpret_cast<const float4*>(
                    &Bs[cur][tx][kk * TN + j]);
                b[j] = v.x; b[j + 1] = v.y; b[j + 2] = v.z; b[j + 3] = v.w;
            }
#pragma unroll
            for (int i = 0; i < TM; ++i)
#pragma unroll
                for (int j = 0; j < TN; ++j)
                    acc[i][j] = fmaf(a[i], b[j], acc[i][j]);
        }
        if (has_next) __syncthreads();
        cur ^= 1;
    }

#pragma unroll
    for (int i = 0; i < TM; ++i) {
        const int m = m0 + ty * TM + i;
#pragma unroll
        for (int j = 0; j < TN; ++j) {
            const int n = n0 + tx * TN + j;
            C[(size_t)m * ldc + n] = acc[i][j] + bias[n];
        }
    }
}

// ---------------------------------------------------------------------------
// Prep: split x into 3 bf16 arrays (same [row][k] layout).
// ---------------------------------------------------------------------------
__global__ __launch_bounds__(256)
void split_x_kernel(const float* __restrict__ x, unsigned short* __restrict__ xh,
                    unsigned short* __restrict__ xm, unsigned short* __restrict__ xl)
{
    const size_t total4 = (size_t)kB * kS * kD / 4;
    for (size_t i4 = blockIdx.x * 256 + threadIdx.x; i4 < total4;
         i4 += (size_t)gridDim.x * 256) {
        const float4 v = *reinterpret_cast<const float4*>(&x[i4 * 4]);
        ushort4 h, m, l;
        split3(v.x, h.x, m.x, l.x);
        split3(v.y, h.y, m.y, l.y);
        split3(v.z, h.z, m.z, l.z);
        split3(v.w, h.w, m.w, l.w);
        *reinterpret_cast<ushort4*>(&xh[i4 * 4]) = h;
        *reinterpret_cast<ushort4*>(&xm[i4 * 4]) = m;
        *reinterpret_cast<ushort4*>(&xl[i4 * 4]) = l;
    }
}

// ---------------------------------------------------------------------------
// Prep: split + transpose W_qkv[:, 0:1536] into Wh/Wm/Wl [n=1536][k=768].
// 64x64 tiles through LDS so both global read and write are coalesced.
// ---------------------------------------------------------------------------
__global__ __launch_bounds__(256)
void split_w_kernel(const float* __restrict__ W,
                    unsigned short* __restrict__ Wh,
                    unsigned short* __restrict__ Wm,
                    unsigned short* __restrict__ Wl)
{
    __shared__ unsigned short Th[64][72], Tm[64][72], Tl[64][72];
    const int k0 = blockIdx.x * 64, n0 = blockIdx.y * 64;
    const int tid = threadIdx.x;

#pragma unroll
    for (int i = 0; i < 16; ++i) {
        const int idx = tid + i * 256;
        const int kk = idx >> 6, nn = idx & 63;
        const float v = W[(size_t)(k0 + kk) * k3D + (n0 + nn)];
        split3(v, Th[nn][kk], Tm[nn][kk], Tl[nn][kk]);
    }
    __syncthreads();
#pragma unroll
    for (int i = 0; i < 16; ++i) {
        const int idx = tid + i * 256;
        const int nn = idx >> 6, kk = idx & 63;
        const size_t o = (size_t)(n0 + nn) * kD + (k0 + kk);
        Wh[o] = Th[nn][kk];
        Wm[o] = Tm[nn][kk];
        Wl[o] = Tl[nn][kk];
    }
}

// ---------------------------------------------------------------------------
// Q,K GEMM via 3x3 bf16-split MFMA (8 product terms, down to 2^-24 — error
// ~1e-6 vs the real dot, same order as frozen-chain-vs-numpy rounding noise).
// Structure & fragment layout copied from the HW-validated V-GEMM (r7-r15).
// BM=128, BN=64, BK=32, 256 thr; single-buffered 45KB LDS (3 blocks/CU).
// ---------------------------------------------------------------------------
__global__ __launch_bounds__(256)
void qk_mfma_kernel(const unsigned short* __restrict__ xh,
                    const unsigned short* __restrict__ xm,
                    const unsigned short* __restrict__ xl,
                    const unsigned short* __restrict__ Wh,
                    const unsigned short* __restrict__ Wm,
                    const unsigned short* __restrict__ Wl,
                    const float* __restrict__ bias, float* __restrict__ C)
{
    using f32x4 = __attribute__((ext_vector_type(4))) float;
    using s16x8 = __attribute__((ext_vector_type(8))) short;

    __shared__ unsigned short Axs[3][128][40];   // 30.0KB
    __shared__ unsigned short Bxs[3][64][40];    // 15.0KB

    const int tid = threadIdx.x;
    const int wave = tid >> 6, lane = tid & 63;
    const int jq = lane & 15, hi = lane >> 4;
    const int n0 = blockIdx.x * 64, m0 = blockIdx.y * 128;

    const unsigned short* Xs[3] = {xh, xm, xl};
    const unsigned short* Ws[3] = {Wh, Wm, Wl};

    f32x4 acc[2][4];
#pragma unroll
    for (int i = 0; i < 2; ++i)
#pragma unroll
        for (int j = 0; j < 4; ++j) acc[i][j] = {0.f, 0.f, 0.f, 0.f};

    for (int kt = 0; kt < kD / 32; ++kt) {
        const int k0 = kt * 32;
        __syncthreads();                         // protect previous reads
        // stage A (128x32 x3) and B (64x32 x3), direct ushort4 copies
#pragma unroll
        for (int s = 0; s < 3; ++s) {
#pragma unroll
            for (int it = 0; it < 4; ++it) {
                const int e = (tid + it * 256) * 4;
                const int row = e >> 5, col = e & 31;
                *reinterpret_cast<ushort4*>(&Axs[s][row][col]) =
                    *reinterpret_cast<const ushort4*>(
                        &Xs[s][(size_t)(m0 + row) * kD + (k0 + col)]);
            }
#pragma unroll
            for (int it = 0; it < 2; ++it) {
                const int e = (tid + it * 256) * 4;
                const int row = e >> 5, col = e & 31;
                *reinterpret_cast<ushort4*>(&Bxs[s][row][col]) =
                    *reinterpret_cast<const ushort4*>(
                        &Ws[s][(size_t)(n0 + row) * kD + (k0 + col)]);
            }
        }
        __syncthreads();

        s16x8 af[2][3];
#pragma unroll
        for (int i = 0; i < 2; ++i)
#pragma unroll
            for (int s = 0; s < 3; ++s)
                af[i][s] = *reinterpret_cast<const s16x8*>(
                    &Axs[s][wave * 32 + i * 16 + jq][hi * 8]);

#pragma unroll
        for (int j = 0; j < 4; ++j) {
            s16x8 bf[3];
#pragma unroll
            for (int s = 0; s < 3; ++s)
                bf[s] = *reinterpret_cast<const s16x8*>(
                    &Bxs[s][j * 16 + jq][hi * 8]);
#pragma unroll
            for (int i = 0; i < 2; ++i) {
                f32x4 c = acc[i][j];
                c = __builtin_amdgcn_mfma_f32_16x16x32_bf16(af[i][0], bf[0], c, 0, 0, 0); // hh
                c = __builtin_amdgcn_mfma_f32_16x16x32_bf16(af[i][1], bf[0], c, 0, 0, 0); // mh
                c = __builtin_amdgcn_mfma_f32_16x16x32_bf16(af[i][0], bf[1], c, 0, 0, 0); // hm
                c = __builtin_amdgcn_mfma_f32_16x16x32_bf16(af[i][2], bf[0], c, 0, 0, 0); // lh
                c = __builtin_amdgcn_mfma_f32_16x16x32_bf16(af[i][1], bf[1], c, 0, 0, 0); // mm
                c = __builtin_amdgcn_mfma_f32_16x16x32_bf16(af[i][0], bf[2], c, 0, 0, 0); // hl
                c = __builtin_amdgcn_mfma_f32_16x16x32_bf16(af[i][2], bf[1], c, 0, 0, 0); // lm
                c = __builtin_amdgcn_mfma_f32_16x16x32_bf16(af[i][1], bf[2], c, 0, 0, 0); // ml
                acc[i][j] = c;
            }
        }
    }

#pragma unroll
    for (int i = 0; i < 2; ++i) {
        const int mbase = m0 + wave * 32 + i * 16 + hi * 4;
#pragma unroll
        for (int j = 0; j < 4; ++j) {
            const int n = n0 + j * 16 + jq;
            const float bv = bias[n];
#pragma unroll
            for (int r = 0; r < 4; ++r)
                C[(size_t)(mbase + r) * k3D + n] = acc[i][j][r] + bv;
        }
    }
}

// ---------------------------------------------------------------------------
// bf16-split MFMA GEMM with bias (V projection + output projection).
// Unchanged from round 10.
// ---------------------------------------------------------------------------
__global__ __launch_bounds__(256)
void gemm_mfma_kernel(const float* __restrict__ A, const float* __restrict__ Bm,
                      const float* __restrict__ bias, float* __restrict__ C,
                      int M, int K, int ldb, int ldc)
{
    using f32x4 = __attribute__((ext_vector_type(4))) float;
    using s16x8 = __attribute__((ext_vector_type(8))) short;
    constexpr int BM = 128, BN = 64, BK = 32;
    constexpr int AST = 40;

    __shared__ unsigned short Ah[2][BM][AST];
    __shared__ unsigned short Al[2][BM][AST];
    __shared__ unsigned short Bh[2][BN][AST];

    const int tid = threadIdx.x;
    const int wave = tid >> 6, lane = tid & 63;
    const int jq = lane & 15, hi = lane >> 4;
    const int m0 = blockIdx.y * BM, n0 = blockIdx.x * BN;

    float4 pa[4], pb[2];
    auto load_tiles = [&](int k0) {
#pragma unroll
        for (int it = 0; it < 4; ++it) {
            const int e = (tid + it * 256) * 4;
            const int row = e / BK, col = e % BK;
            pa[it] = *reinterpret_cast<const float4*>(
                &A[(size_t)(m0 + row) * K + (k0 + col)]);
        }
#pragma unroll
        for (int it = 0; it < 2; ++it) {
            const int e = (tid + it * 256) * 4;
            const int krow = e / BN, ncol = e % BN;
            pb[it] = *reinterpret_cast<const float4*>(
                &Bm[(size_t)(k0 + krow) * ldb + (n0 + ncol)]);
        }
    };
    auto commit = [&](int buf) {
#pragma unroll
        for (int it = 0; it < 4; ++it) {
            const int e = (tid + it * 256) * 4;
            const int row = e / BK, col = e % BK;
            const float v[4] = {pa[it].x, pa[it].y, pa[it].z, pa[it].w};
            ushort4 uh, ul;
            unsigned short* ph = &uh.x;
            unsigned short* pl = &ul.x;
#pragma unroll
            for (int r = 0; r < 4; ++r) {
                const short hb = bf16rne_s(v[r]);
                ph[r] = (unsigned short)hb;
                pl[r] = (unsigned short)bf16rne_s(v[r] - bf16tof(hb));
            }
            *reinterpret_cast<ushort4*>(&Ah[buf][row][col]) = uh;
            *reinterpret_cast<ushort4*>(&Al[buf][row][col]) = ul;
        }
#pragma unroll
        for (int it = 0; it < 2; ++it) {
            const int e = (tid + it * 256) * 4;
            const int krow = e / BN, ncol = e % BN;
            Bh[buf][ncol + 0][krow] = (unsigned short)bf16rne_s(pb[it].x);
            Bh[buf][ncol + 1][krow] = (unsigned short)bf16rne_s(pb[it].y);
            Bh[buf][ncol + 2][krow] = (unsigned short)bf16rne_s(pb[it].z);
            Bh[buf][ncol + 3][krow] = (unsigned short)bf16rne_s(pb[it].w);
        }
    };

    f32x4 acc[2][4];
#pragma unroll
    for (int i = 0; i < 2; ++i)
#pragma unroll
        for (int j = 0; j < 4; ++j) acc[i][j] = {0.f, 0.f, 0.f, 0.f};

    load_tiles(0);
    commit(0);
    load_tiles(BK);
    __syncthreads();

    int cur = 0;
    for (int k0 = 0; k0 < K; k0 += BK) {
        const bool has_next = (k0 + BK < K);
        if (has_next) {
            commit(cur ^ 1);
            if (k0 + 2 * BK < K) load_tiles(k0 + 2 * BK);
        }
        s16x8 ahf[2], alf[2], bhf[4];
#pragma unroll
        for (int i = 0; i < 2; ++i) {
            ahf[i] = *reinterpret_cast<const s16x8*>(
                &Ah[cur][wave * 32 + i * 16 + jq][hi * 8]);
            alf[i] = *reinterpret_cast<const s16x8*>(
                &Al[cur][wave * 32 + i * 16 + jq][hi * 8]);
        }
#pragma unroll
        for (int j = 0; j < 4; ++j)
            bhf[j] = *reinterpret_cast<const s16x8*>(
                &Bh[cur][j * 16 + jq][hi * 8]);
#pragma unroll
        for (int i = 0; i < 2; ++i)
#pragma unroll
            for (int j = 0; j < 4; ++j) {
                f32x4 c = acc[i][j];
                c = __builtin_amdgcn_mfma_f32_16x16x32_bf16(ahf[i], bhf[j], c, 0, 0, 0);
                c = __builtin_amdgcn_mfma_f32_16x16x32_bf16(alf[i], bhf[j], c, 0, 0, 0);
                acc[i][j] = c;
            }
        if (has_next) __syncthreads();
        cur ^= 1;
    }

#pragma unroll
    for (int i = 0; i < 2; ++i) {
        const int mbase = m0 + wave * 32 + i * 16 + hi * 4;
#pragma unroll
        for (int j = 0; j < 4; ++j) {
            const int n = n0 + j * 16 + jq;
            const float bv = bias[n];
#pragma unroll
            for (int r = 0; r < 4; ++r)
                C[(size_t)(mbase + r) * ldc + n] = acc[i][j][r] + bv;
        }
    }
}

// ---------------------------------------------------------------------------
// Per-key V suffix sums: vsuf[b][h][k][d] = sum_{j>=k} V[b][j][h*64+d].
// ---------------------------------------------------------------------------
__global__ __launch_bounds__(256)
void vsuf_kernel(const float* __restrict__ qkv, float* __restrict__ vsuf)
{
    const int h = blockIdx.x, b = blockIdx.y;
    const int lane = threadIdx.x & 63, wave = threadIdx.x >> 6;
    const float* vp = qkv + (size_t)b * kS * k3D + 2 * kD + h * kHD;
    float* op = vsuf + (size_t)(b * kH + h) * kS * kHD;
    __shared__ float csum[4][64];

    const int kBeg = wave * 512, kEnd = kBeg + 512;
    float s = 0.0f;
#pragma unroll 8
    for (int k = kBeg; k < kEnd; ++k)
        s += vp[(size_t)k * k3D + lane];
    csum[wave][lane] = s;
    __syncthreads();

    float run = 0.0f;
    for (int w = wave + 1; w < 4; ++w) run += csum[w][lane];
#pragma unroll 8
    for (int k = kEnd - 1; k >= kBeg; --k) {
        run += vp[(size_t)k * k3D + lane];
        op[(size_t)k * kHD + lane] = run;
    }
}

// ---------------------------------------------------------------------------
// Attention: TWO-PASS bf16-MFMA approximate scan + exact-fp32 rescue.
// Unchanged from round 14/15 (measured-good).
// ---------------------------------------------------------------------------
__global__ __launch_bounds__(256, 3)
void attn_mfma_kernel(const float* __restrict__ qkv,
                      const float* __restrict__ vsuf,
                      float* __restrict__ ctx)
{
    using f32x4 = __attribute__((ext_vector_type(4))) float;
    using s16x8 = __attribute__((ext_vector_type(8))) short;

    const int id = blockIdx.x;
    const int bh = id % (kB * kH);
    const int t  = id / (kB * kH);
    const int b = bh / kH, h = bh % kH;

    const int tid = threadIdx.x;
    const int wave = tid >> 6, lane = tid & 63;
    const int jq = lane & 15, hi = lane >> 4;
    const int qrow = wave * 16 + jq;
    const int qglob = t * 64 + qrow;

    __shared__ float Qf[64][68];
    __shared__ float Kf[64][68];
    __shared__ unsigned short Kb[64][72];
    __shared__ float Msh[64];
    __shared__ float MgS[64];
    __shared__ int   CgS[64], I0S[64], I1S[64];

    const float* qp = qkv + (size_t)b * kS * k3D + h * kHD;
    const float* kp = qp + kD;
    const float* vp = qp + 2 * kD;

#pragma unroll
    for (int i = 0; i < 4; ++i) {
        const int f4 = tid + i * 256;
        const int r = f4 >> 4, d4 = f4 & 15;
        float4 v = *reinterpret_cast<const float4*>(
            &qp[(size_t)(t * 64 + r) * k3D + d4 * 4]);
        v.x *= 0.125f; v.y *= 0.125f; v.z *= 0.125f; v.w *= 0.125f;
        *reinterpret_cast<float4*>(&Qf[r][d4 * 4]) = v;
    }
    __syncthreads();

    auto mkfrag = [&](const float* p) {
        const float4 a = *reinterpret_cast<const float4*>(p);
        const float4 c = *reinterpret_cast<const float4*>(p + 4);
        s16x8 r;
        r[0] = bf16rne_s(a.x); r[1] = bf16rne_s(a.y);
        r[2] = bf16rne_s(a.z); r[3] = bf16rne_s(a.w);
        r[4] = bf16rne_s(c.x); r[5] = bf16rne_s(c.y);
        r[6] = bf16rne_s(c.z); r[7] = bf16rne_s(c.w);
        return r;
    };

    const s16x8 bq0 = mkfrag(&Qf[qrow][hi * 8]);
    const s16x8 bq1 = mkfrag(&Qf[qrow][32 + hi * 8]);

    auto stage_kb = [&](int kt) {
#pragma unroll
        for (int i = 0; i < 4; ++i) {
            const int f4 = tid + i * 256;
            const int r = f4 >> 4, d4 = f4 & 15;
            const float4 v = *reinterpret_cast<const float4*>(
                &kp[(size_t)(kt * 64 + r) * k3D + d4 * 4]);
            ushort4 u;
            u.x = (unsigned short)bf16rne_s(v.x);
            u.y = (unsigned short)bf16rne_s(v.y);
            u.z = (unsigned short)bf16rne_s(v.z);
            u.w = (unsigned short)bf16rne_s(v.w);
            *reinterpret_cast<ushort4*>(&Kb[r][d4 * 4]) = u;
        }
    };
    auto stage_both = [&](int kt) {
#pragma unroll
        for (int i = 0; i < 4; ++i) {
            const int f4 = tid + i * 256;
            const int r = f4 >> 4, d4 = f4 & 15;
            const float4 v = *reinterpret_cast<const float4*>(
                &kp[(size_t)(kt * 64 + r) * k3D + d4 * 4]);
            *reinterpret_cast<float4*>(&Kf[r][d4 * 4]) = v;
            ushort4 u;
            u.x = (unsigned short)bf16rne_s(v.x);
            u.y = (unsigned short)bf16rne_s(v.y);
            u.z = (unsigned short)bf16rne_s(v.z);
            u.w = (unsigned short)bf16rne_s(v.w);
            *reinterpret_cast<ushort4*>(&Kb[r][d4 * 4]) = u;
        }
    };

    auto score_tile = [&](f32x4* acc) {
#pragma unroll
        for (int g = 0; g < 4; ++g) {
            const s16x8 a0 = *reinterpret_cast<const s16x8*>(
                &Kb[g * 16 + jq][hi * 8]);
            const s16x8 a1 = *reinterpret_cast<const s16x8*>(
                &Kb[g * 16 + jq][32 + hi * 8]);
            f32x4 c = {0.f, 0.f, 0.f, 0.f};
            c = __builtin_amdgcn_mfma_f32_16x16x32_bf16(a0, bq0, c, 0, 0, 0);
            c = __builtin_amdgcn_mfma_f32_16x16x32_bf16(a1, bq1, c, 0, 0, 0);
            acc[g] = c;
        }
    };

    // ---- pass 1: approximate per-query causal max ----
    float mt = -INFINITY;
    for (int kt = 0; kt <= t; ++kt) {
        __syncthreads();
        stage_kb(kt);
        __syncthreads();
        f32x4 acc[4];
        score_tile(acc);
#pragma unroll
        for (int g = 0; g < 4; ++g)
#pragma unroll
            for (int r = 0; r < 4; ++r) {
                const int key = kt * 64 + g * 16 + hi * 4 + r;
                if (key <= qglob) mt = fmaxf(mt, acc[g][r]);
            }
    }
    mt = fmaxf(mt, __shfl_xor(mt, 16));
    mt = fmaxf(mt, __shfl_xor(mt, 32));
    if (hi == 0) Msh[wave * 16 + jq] = mt;
    __syncthreads();
    const float thr = Msh[wave * 16 + jq] - kDelta;

    // ---- pass 2: exact rescue of candidates (fp32 chain from LDS Kf) ----
    float m = -INFINITY;
    int cnt = 0, i0 = -1, i1 = -1;
    for (int kt = 0; kt <= t; ++kt) {
        __syncthreads();
        stage_both(kt);
        __syncthreads();
        f32x4 acc[4];
        score_tile(acc);
#pragma unroll
        for (int g = 0; g < 4; ++g)
#pragma unroll
            for (int r = 0; r < 4; ++r) {
                const int key = kt * 64 + g * 16 + hi * 4 + r;
                if (key <= qglob && acc[g][r] > thr) {
                    const float* qr = &Qf[qrow][0];
                    const float* kr = &Kf[key - kt * 64][0];
                    float dot = 0.0f;
#pragma unroll
                    for (int d4 = 0; d4 < 16; ++d4) {
                        const float4 q4 = *reinterpret_cast<const float4*>(qr + d4 * 4);
                        const float4 k4 = *reinterpret_cast<const float4*>(kr + d4 * 4);
                        dot = fmaf(q4.x, k4.x, dot);
                        dot = fmaf(q4.y, k4.y, dot);
                        dot = fmaf(q4.z, k4.z, dot);
                        dot = fmaf(q4.w, k4.w, dot);
                    }
                    const float s = mask_affine(dot);
                    const bool upd = (s > m), tie = (s == m);
                    i1 = upd ? -1 : ((tie && cnt == 1) ? key : i1);
                    i0 = upd ? key : i0;
                    cnt = upd ? 1 : (tie ? cnt + 1 : cnt);
                    m = upd ? s : m;
                }
            }
    }

#pragma unroll
    for (int off = 16; off <= 32; off <<= 1) {
        const float mo = __shfl_xor(m, off);
        const int co = __shfl_xor(cnt, off);
        const int o0 = __shfl_xor(i0, off);
        const int o1 = __shfl_xor(i1, off);
        if (mo > m) { m = mo; cnt = co; i0 = o0; i1 = o1; }
        else if (mo == m && co > 0) {
            if (cnt == 0) { i0 = o0; i1 = o1; }
            else if (cnt == 1) { i1 = o0; }
            cnt += co;
        }
    }
    if (hi == 0) {
        MgS[wave * 16 + jq] = m; CgS[wave * 16 + jq] = cnt;
        I0S[wave * 16 + jq] = i0; I1S[wave * 16 + jq] = i1;
    }
    __syncthreads();

    const int qloc = tid >> 2, qtr = tid & 3;
    const int qi = t * 64 + qloc;
    float mg = MgS[qloc];
    int fcnt = CgS[qloc], f0 = I0S[qloc], f1 = I1S[qloc];

    bool addsuf = false;
    if (qi < kS - 1) {
        const bool lt = (mg < kNeg), eq = (mg == kNeg);
        if (lt)      { fcnt = kS - 1 - qi; f0 = -1; f1 = -1; addsuf = true; }
        else if (eq) { fcnt += kS - 1 - qi; addsuf = true; }
    }

    float4 a4[4];
#pragma unroll
    for (int i = 0; i < 4; ++i) a4[i] = {0.f, 0.f, 0.f, 0.f};

    if (f0 >= 0) {
        const float* vr = vp + (size_t)f0 * k3D + qtr * 16;
#pragma unroll
        for (int i = 0; i < 4; ++i) {
            const float4 v = *reinterpret_cast<const float4*>(vr + i * 4);
            a4[i].x += v.x; a4[i].y += v.y; a4[i].z += v.z; a4[i].w += v.w;
        }
    }
    if (f1 >= 0) {
        const float* vr = vp + (size_t)f1 * k3D + qtr * 16;
#pragma unroll
        for (int i = 0; i < 4; ++i) {
            const float4 v = *reinterpret_cast<const float4*>(vr + i * 4);
            a4[i].x += v.x; a4[i].y += v.y; a4[i].z += v.z; a4[i].w += v.w;
        }
    }
    if (addsuf) {
        const float* sp = vsuf + ((size_t)(b * kH + h) * kS + (qi + 1)) * kHD
                          + qtr * 16;
#pragma unroll
        for (int i = 0; i < 4; ++i) {
            const float4 v = *reinterpret_cast<const float4*>(sp + i * 4);
            a4[i].x += v.x; a4[i].y += v.y; a4[i].z += v.z; a4[i].w += v.w;
        }
    }

    float* op = ctx + ((size_t)b * kS + qi) * kD + h * kHD + qtr * 16;
    const float fc = (float)fcnt;
#pragma unroll
    for (int i = 0; i < 4; ++i) {
        const float4 r = {a4[i].x / fc, a4[i].y / fc, a4[i].z / fc, a4[i].w / fc};
        *reinterpret_cast<float4*>(op + i * 4) = r;
    }
}

// ---------------------------------------------------------------------------
extern "C" void kernel_launch(void* const* d_in, const int* in_sizes, int n_in,
                              void* d_out, int out_size, void* d_ws, size_t ws_size,
                              hipStream_t stream)
{
    const float* x     = (const float*)d_in[0];
    const float* W_qkv = (const float*)d_in[1];
    const float* b_qkv = (const float*)d_in[2];
    const float* W_o   = (const float*)d_in[3];
    const float* b_o   = (const float*)d_in[4];
    float* out = (float*)d_out;

    char* ws = (char*)d_ws;
    float* qkv  = (float*)(ws + kOfsQkv);
    float* ctx  = (float*)(ws + kOfsCtx);
    float* vsuf = out;   // 25.2MB in d_out, overwritten by final GEMM

    if (ws_size >= kNeedWs) {
        // ---- MFMA path: 3x3 bf16-split exact-grade Q,K GEMM ----
        unsigned short* xh = (unsigned short*)(ws + kOfsXh);
        unsigned short* xm = xh + (size_t)kB * kS * kD;
        unsigned short* xl = xm + (size_t)kB * kS * kD;
        unsigned short* Wh = (unsigned short*)(ws + kOfsWh);
        unsigned short* Wm = Wh + (size_t)kD * kNQK;
        unsigned short* Wl = Wm + (size_t)kD * kNQK;

        split_x_kernel<<<dim3(1024), 256, 0, stream>>>(x, xh, xm, xl);
        split_w_kernel<<<dim3(kD / 64, kNQK / 64), 256, 0, stream>>>(
            W_qkv, Wh, Wm, Wl);
        qk_mfma_kernel<<<dim3(kNQK / 64, (kB * kS) / 128), 256, 0, stream>>>(
            xh, xm, xl, Wh, Wm, Wl, b_qkv, qkv);
    } else {
        // ---- fallback: exact fp32 QK GEMM (bit-identical to rounds 1-15) ----
        dim3 grid(kNQK / 128, (kB * kS) / 128);
        gemm_bias_kernel<128, 128, 16, 8, 8><<<grid, 256, 0, stream>>>(
            x, W_qkv, b_qkv, qkv, kB * kS, kD, k3D, k3D);
    }
    // V columns: staged-split bf16 MFMA GEMM
    {
        dim3 grid(kD / 64, (kB * kS) / 128);
        gemm_mfma_kernel<<<grid, 256, 0, stream>>>(
            x, W_qkv + 2 * kD, b_qkv + 2 * kD, qkv + 2 * kD,
            kB * kS, kD, k3D, k3D);
    }
    // per-key V suffix sums
    {
        dim3 grid(kH, kB);
        vsuf_kernel<<<grid, 256, 0, stream>>>(qkv, vsuf);
    }
    // attention: two-pass MFMA approx scan + exact fp32 rescue
    {
        attn_mfma_kernel<<<dim3((kS / 64) * kB * kH), 256, 0, stream>>>(
            qkv, vsuf, ctx);
    }
    // out = ctx @ W_o + b_o
    {
        dim3 grid(kD / 64, (kB * kS) / 128);
        gemm_mfma_kernel<<<grid, 256, 0, stream>>>(
            ctx, W_o, b_o, out, kB * kS, kD, kD, kD);
    }
}